// Round 4
// baseline (12965.424 us; speedup 1.0000x reference)
//
#include <hip/hip_runtime.h>
#include <math.h>

#define HH 512
#define BB 64
#define SS 48
#define EE 512
#define G4 2048
#define SC 24
#define EPSF 1e-5f
#define NBLK 256

// ======== grid-wide sense barrier (256 blocks, device-scope) ========
__device__ __forceinline__ void gridbar(int* cnt, int* gen) {
  __syncthreads();
  if (threadIdx.x == 0) {
    __threadfence();
    int g = __hip_atomic_load(gen, __ATOMIC_RELAXED, __HIP_MEMORY_SCOPE_AGENT);
    int old = __hip_atomic_fetch_add(cnt, 1, __ATOMIC_ACQ_REL, __HIP_MEMORY_SCOPE_AGENT);
    if (old == NBLK - 1) {
      __hip_atomic_store(cnt, 0, __ATOMIC_RELAXED, __HIP_MEMORY_SCOPE_AGENT);
      __hip_atomic_store(gen, g + 1, __ATOMIC_RELEASE, __HIP_MEMORY_SCOPE_AGENT);
    } else {
      long spins = 0;
      while (__hip_atomic_load(gen, __ATOMIC_ACQUIRE, __HIP_MEMORY_SCOPE_AGENT) == g) {
        __builtin_amdgcn_s_sleep(8);
        if (++spins > (1L << 21)) break;   // safety bailout (~0.5 s) — avoids harness hang
      }
    }
  }
  __syncthreads();
  __threadfence();
}

// ======== phase A: layer-0 input projection for one 24-step chunk ========
// Gc rows m = d*(B*SC) + b*SC + tl ; x row b*SS + s, s = d ? SS-1-t0-tl : t0+tl
__global__ __launch_bounds__(256)
void gemm_ih0(const float* __restrict__ x, const float* __restrict__ w_ih0,
              float* __restrict__ Gc, int t0) {
  __shared__ float As[16][65];
  __shared__ float Bs[16][65];
  const int m0 = blockIdx.y * 64;
  const int d  = m0 / (BB * SC);
  const float* Wm = w_ih0 + (size_t)d * G4 * EE;
  const int bn = blockIdx.x * 64;
  const int tid = threadIdx.x;
  const int lrow = tid >> 2;
  const int lkk  = (tid & 3) << 2;
  const int tx = tid & 15;
  const int ty = tid >> 4;
  int m  = m0 + lrow;
  int r  = m - d * (BB * SC);
  int b  = r / SC;
  int tl = r - b * SC;
  int s  = d ? (SS - 1 - t0 - tl) : (t0 + tl);
  const float* arow = x + ((size_t)b * SS + s) * EE;

  float acc[4][4] = {};
  for (int k0 = 0; k0 < EE; k0 += 16) {
    float4 av = *(const float4*)(arow + k0 + lkk);
    float4 bv = *(const float4*)(Wm + (size_t)(bn + lrow) * EE + k0 + lkk);
    As[lkk+0][lrow] = av.x; As[lkk+1][lrow] = av.y; As[lkk+2][lrow] = av.z; As[lkk+3][lrow] = av.w;
    Bs[lkk+0][lrow] = bv.x; Bs[lkk+1][lrow] = bv.y; Bs[lkk+2][lrow] = bv.z; Bs[lkk+3][lrow] = bv.w;
    __syncthreads();
    #pragma unroll
    for (int k = 0; k < 16; ++k) {
      float a[4], bbv[4];
      #pragma unroll
      for (int i = 0; i < 4; ++i) a[i] = As[k][ty*4+i];
      #pragma unroll
      for (int j = 0; j < 4; ++j) bbv[j] = Bs[k][tx*4+j];
      #pragma unroll
      for (int i = 0; i < 4; ++i)
        #pragma unroll
        for (int j = 0; j < 4; ++j) acc[i][j] += a[i]*bbv[j];
    }
    __syncthreads();
  }
  for (int i = 0; i < 4; ++i)
    for (int j = 0; j < 4; ++j)
      Gc[(size_t)(m0 + ty*4 + i) * G4 + bn + tx*4 + j] = acc[i][j];
}

// ======== in-place LayerNorm on rows of 2048 ========
__global__ __launch_bounds__(256)
void ln_rows(float* __restrict__ X, const float* __restrict__ gamma,
             const float* __restrict__ beta, int rows_per_d) {
  __shared__ float red[8];
  const int row = blockIdx.x;
  const int d = row / rows_per_d;
  float* xr = X + (size_t)row * G4;
  const float* gg = gamma + (size_t)d * G4;
  const float* bb = beta  + (size_t)d * G4;
  float s = 0.f, q = 0.f;
  float v[8];
  #pragma unroll
  for (int it = 0; it < 8; ++it) {
    float xv = xr[threadIdx.x + it*256];
    v[it] = xv; s += xv; q += xv*xv;
  }
  #pragma unroll
  for (int off = 32; off > 0; off >>= 1) { s += __shfl_down(s, off); q += __shfl_down(q, off); }
  int lane = threadIdx.x & 63, wid = threadIdx.x >> 6;
  if (lane == 0) { red[wid] = s; red[4+wid] = q; }
  __syncthreads();
  float ts = red[0]+red[1]+red[2]+red[3];
  float tq = red[4]+red[5]+red[6]+red[7];
  float mu = ts * (1.f/G4);
  float rstd = rsqrtf(tq*(1.f/G4) - mu*mu + EPSF);
  #pragma unroll
  for (int it = 0; it < 8; ++it) {
    int jc = threadIdx.x + it*256;
    xr[jc] = (v[it]-mu)*rstd*gg[jc] + bb[jc];
  }
}

// ======== W_hh [2][2048][512] -> Wt [d][512][2048] (fp32 transpose) ========
__global__ __launch_bounds__(256)
void transpose_f32(const float* __restrict__ src0, float* __restrict__ dst) {
  __shared__ float tile[64][65];
  const int dd = blockIdx.z;
  const float* src = src0 + (size_t)dd * G4 * HH;
  float* dst_d = dst + (size_t)dd * HH * G4;
  const int bn = blockIdx.x * 64;
  const int bk = blockIdx.y * 64;
  const int tx = threadIdx.x & 63;
  const int ty = threadIdx.x >> 6;
  #pragma unroll
  for (int jj = 0; jj < 16; ++jj) {
    int r = ty * 16 + jj;
    tile[r][tx] = src[(size_t)(bn + r) * HH + bk + tx];
  }
  __syncthreads();
  #pragma unroll
  for (int jj = 0; jj < 16; ++jj) {
    int r = ty * 16 + jj;
    dst_d[(size_t)(bk + r) * G4 + bn + tx] = tile[tx][r];
  }
}

// ======== persistent scan kernel: 256 blocks, weights in VGPRs ========
// GEMM role: block = (d = bb&1, nb = (bb>>1)&31, bq = bb>>6); wave kq = tid>>6,
//            lane = n-col; wreg[128] = Wt[d][kq*128 + i][nb*64 + lane].
// Cell role (bb < 128): d = bb&1, b = bb>>1; c kept in regs.
__global__ __launch_bounds__(256, 1)
void persist(const float* Wt, const float* G,
             size_t g_db_stride, size_t g_t_stride,
             const float* lnhg, const float* lnhb,
             const float* lnog, const float* lnob,
             float* hbuf, float* cbuf, float* Rbuf, float2* Rsums,
             float* fout, int nsteps, int write_final, int load_c,
             int mode1, const float* w_ih1, const float* xcb, float* g1pre,
             const float* ln_ih1_g, const float* ln_ih1_b,
             int* bar) {
  __shared__ float part[4][16][64];   // 16 KB
  __shared__ float redR[16][64];      // 4 KB
  __shared__ float sred[16];
  __shared__ float bc[2];

  int* cnt = bar;
  int* gen = bar + 1;

  const int bb = blockIdx.x;
  const int tid = threadIdx.x;
  const int lane = tid & 63;
  const int kq = tid >> 6;
  const int d  = bb & 1;
  const int nb = (bb >> 1) & 31;
  const int bq = bb >> 6;
  const int n = nb * 64 + lane;

  // ---- mode1 preamble: layer-1 projection + zero h/c + LN(g1pre) ----
  float c0 = 0.f, c1 = 0.f;
  if (mode1) {
    const int pb_ = tid >> 2, ns = tid & 3;
    const int nbp = bb >> 1;            // [0,128) — 16 n-cols per block
    const float* xrow = xcb + (size_t)pb_ * 1024;
    const size_t nbase = (size_t)d * G4 + (size_t)nbp * 16 + ns;
    const float* w0 = w_ih1 + (nbase + 0)  * 1024;
    const float* w1 = w_ih1 + (nbase + 4)  * 1024;
    const float* w2 = w_ih1 + (nbase + 8)  * 1024;
    const float* w3 = w_ih1 + (nbase + 12) * 1024;
    float a0=0.f, a1=0.f, a2=0.f, a3=0.f;
    for (int k = 0; k < 1024; k += 4) {
      float4 xv = *(const float4*)(xrow + k);
      float4 v0 = *(const float4*)(w0 + k);
      float4 v1 = *(const float4*)(w1 + k);
      float4 v2 = *(const float4*)(w2 + k);
      float4 v3 = *(const float4*)(w3 + k);
      a0 += xv.x*v0.x + xv.y*v0.y + xv.z*v0.z + xv.w*v0.w;
      a1 += xv.x*v1.x + xv.y*v1.y + xv.z*v1.z + xv.w*v1.w;
      a2 += xv.x*v2.x + xv.y*v2.y + xv.z*v2.z + xv.w*v2.w;
      a3 += xv.x*v3.x + xv.y*v3.y + xv.z*v3.z + xv.w*v3.w;
    }
    float* grow = g1pre + ((size_t)d * BB + pb_) * G4 + (size_t)nbp * 16 + ns;
    grow[0] = a0; grow[4] = a1; grow[8] = a2; grow[12] = a3;
    if (bb < 128) {   // zero h for scan start
      size_t rowdb = (size_t)(bb & 1) * BB + (bb >> 1);
      hbuf[rowdb * HH + tid] = 0.f;
      hbuf[rowdb * HH + tid + 256] = 0.f;
    }
    gridbar(cnt, gen);
    if (bb < 128) {   // LN(g1pre) row
      const int pd = bb & 1, pb = bb >> 1;
      float* xr = g1pre + ((size_t)pd * BB + pb) * G4;
      const float* gg = ln_ih1_g + (size_t)pd * G4;
      const float* be = ln_ih1_b + (size_t)pd * G4;
      float s = 0.f, q = 0.f;
      float v[8];
      #pragma unroll
      for (int it = 0; it < 8; ++it) {
        float xv = xr[tid + it*256];
        v[it] = xv; s += xv; q += xv*xv;
      }
      #pragma unroll
      for (int off = 32; off > 0; off >>= 1) { s += __shfl_down(s, off); q += __shfl_down(q, off); }
      if (lane == 0) { sred[kq] = s; sred[8+kq] = q; }
      __syncthreads();
      float ts = sred[0]+sred[1]+sred[2]+sred[3];
      float tq = sred[8]+sred[9]+sred[10]+sred[11];
      __syncthreads();
      float mu = ts * (1.f/G4);
      float rstd = rsqrtf(tq*(1.f/G4) - mu*mu + EPSF);
      #pragma unroll
      for (int it = 0; it < 8; ++it) {
        int jc = tid + it*256;
        xr[jc] = (v[it]-mu)*rstd*gg[jc] + be[jc];
      }
    }
    gridbar(cnt, gen);
  }

  // ---- load recurrent weights into registers (once) ----
  float wreg[128];
  {
    const float* wcol = Wt + ((size_t)d * HH + (size_t)kq * 128) * G4 + n;
    #pragma unroll
    for (int i = 0; i < 128; ++i) wreg[i] = wcol[(size_t)i * G4];
  }

  // ---- cell-state init ----
  if (bb < 128 && load_c) {
    size_t rowdb = (size_t)(bb & 1) * BB + (bb >> 1);
    c0 = cbuf[rowdb * HH + tid];
    c1 = cbuf[rowdb * HH + tid + 256];
  }

  // ================= scan loop =================
  for (int t = 0; t < nsteps; ++t) {
    // ---- GEMM: R partial over k-slice, weights from registers ----
    for (int b = 0; b < 16; ++b) {
      const float4* hp = (const float4*)(hbuf + ((size_t)(d*BB + bq*16 + b)) * HH + kq*128);
      float p0=0.f, p1=0.f, p2=0.f, p3=0.f;
      #pragma unroll
      for (int j = 0; j < 32; ++j) {
        float4 hv = hp[j];
        p0 += hv.x * wreg[4*j+0];
        p1 += hv.y * wreg[4*j+1];
        p2 += hv.z * wreg[4*j+2];
        p3 += hv.w * wreg[4*j+3];
      }
      part[kq][b][lane] = (p0+p1) + (p2+p3);
    }
    __syncthreads();
    // ---- k-reduce + write R + stash for LN partials ----
    for (int c = tid; c < 1024; c += 256) {
      int b = c >> 6, nl = c & 63;
      float v = part[0][b][nl] + part[1][b][nl] + part[2][b][nl] + part[3][b][nl];
      redR[b][nl] = v;
      Rbuf[((size_t)(d*BB + bq*16 + b)) * G4 + (size_t)nb*64 + nl] = v;
    }
    __syncthreads();
    // ---- per-b LN partial sums over this block's 64 n ----
    #pragma unroll
    for (int bi = 0; bi < 4; ++bi) {
      int b = kq*4 + bi;
      float v = redR[b][lane];
      float s = v, q = v*v;
      #pragma unroll
      for (int off = 32; off > 0; off >>= 1) { s += __shfl_down(s, off); q += __shfl_down(q, off); }
      if (lane == 0)
        Rsums[((size_t)(d*BB + bq*16 + b)) * 32 + nb] = make_float2(s, q);
    }
    gridbar(cnt, gen);   // R + partials visible

    // ---- cell update role ----
    if (bb < 128) {
      const int pd = bb & 1, pb = bb >> 1;
      const size_t rowdb = (size_t)pd * BB + pb;
      float s = 0.f, q = 0.f;
      if (tid < 32) { float2 v = Rsums[rowdb*32 + tid]; s = v.x; q = v.y; }
      #pragma unroll
      for (int off = 16; off > 0; off >>= 1) { s += __shfl_down(s, off); q += __shfl_down(q, off); }
      if (tid == 0) { bc[0] = s; bc[1] = q; }
      __syncthreads();
      float mu   = bc[0] * (1.f/G4);
      float rstd = rsqrtf(bc[1]*(1.f/G4) - mu*mu + EPSF);
      const float* Rrow = Rbuf + rowdb * G4;
      const float* grow = G + rowdb * g_db_stride + (size_t)t * g_t_stride;
      const float* hg = lnhg + (size_t)pd * G4;
      const float* hb = lnhb + (size_t)pd * G4;
      const float* og = lnog + (size_t)pd * HH;
      const float* ob = lnob + (size_t)pd * HH;
      const int n0 = tid, n1 = tid + 256;
      float gi0 = grow[n0]        + (Rrow[n0]        - mu)*rstd*hg[n0]        + hb[n0];
      float gf0 = grow[HH+n0]     + (Rrow[HH+n0]     - mu)*rstd*hg[HH+n0]     + hb[HH+n0];
      float go0 = grow[2*HH+n0]   + (Rrow[2*HH+n0]   - mu)*rstd*hg[2*HH+n0]   + hb[2*HH+n0];
      float gt0 = grow[3*HH+n0]   + (Rrow[3*HH+n0]   - mu)*rstd*hg[3*HH+n0]   + hb[3*HH+n0];
      float gi1 = grow[n1]        + (Rrow[n1]        - mu)*rstd*hg[n1]        + hb[n1];
      float gf1 = grow[HH+n1]     + (Rrow[HH+n1]     - mu)*rstd*hg[HH+n1]     + hb[HH+n1];
      float go1 = grow[2*HH+n1]   + (Rrow[2*HH+n1]   - mu)*rstd*hg[2*HH+n1]   + hb[2*HH+n1];
      float gt1 = grow[3*HH+n1]   + (Rrow[3*HH+n1]   - mu)*rstd*hg[3*HH+n1]   + hb[3*HH+n1];
      float iv0 = 1.f/(1.f+expf(-gi0)), fv0 = 1.f/(1.f+expf(-gf0));
      float ov0 = 1.f/(1.f+expf(-go0)), gv0 = tanhf(gt0);
      float iv1 = 1.f/(1.f+expf(-gi1)), fv1 = 1.f/(1.f+expf(-gf1));
      float ov1 = 1.f/(1.f+expf(-go1)), gv1 = tanhf(gt1);
      c0 = fv0*c0 + iv0*gv0;
      c1 = fv1*c1 + iv1*gv1;
      float cs = c0 + c1, cq = c0*c0 + c1*c1;
      #pragma unroll
      for (int off = 32; off > 0; off >>= 1) { cs += __shfl_down(cs, off); cq += __shfl_down(cq, off); }
      if (lane == 0) { sred[kq] = cs; sred[8+kq] = cq; }
      __syncthreads();
      float tcs = sred[0]+sred[1]+sred[2]+sred[3];
      float tcq = sred[8]+sred[9]+sred[10]+sred[11];
      __syncthreads();
      float muc = tcs * (1.f/HH);
      float rsc = rsqrtf(tcq*(1.f/HH) - muc*muc + EPSF);
      float h0 = ov0 * tanhf((c0 - muc)*rsc*og[n0] + ob[n0]);
      float h1 = ov1 * tanhf((c1 - muc)*rsc*og[n1] + ob[n1]);
      hbuf[rowdb * HH + n0] = h0;
      hbuf[rowdb * HH + n1] = h1;
      if (write_final && t == nsteps - 1) {
        fout[(size_t)pb * 1024 + (size_t)pd * HH + n0] = h0;
        fout[(size_t)pb * 1024 + (size_t)pd * HH + n1] = h1;
      }
    }
    gridbar(cnt, gen);   // h visible for next step
  }

  // ---- save cell state for next chunk ----
  if (bb < 128) {
    size_t rowdb = (size_t)(bb & 1) * BB + (bb >> 1);
    cbuf[rowdb * HH + tid] = c0;
    cbuf[rowdb * HH + tid + 256] = c1;
  }
}

extern "C" void kernel_launch(void* const* d_in, const int* in_sizes, int n_in,
                              void* d_out, int out_size, void* d_ws, size_t ws_size,
                              hipStream_t stream) {
  const float* x        = (const float*)d_in[0];
  const float* w_ih0    = (const float*)d_in[2];
  const float* w_hh0    = (const float*)d_in[3];
  const float* ln_ih0_g = (const float*)d_in[4];
  const float* ln_ih0_b = (const float*)d_in[5];
  const float* ln_hh0_g = (const float*)d_in[6];
  const float* ln_hh0_b = (const float*)d_in[7];
  const float* ln_ho0_g = (const float*)d_in[8];
  const float* ln_ho0_b = (const float*)d_in[9];
  const float* w_ih1    = (const float*)d_in[10];
  const float* w_hh1    = (const float*)d_in[11];
  const float* ln_ih1_g = (const float*)d_in[12];
  const float* ln_ih1_b = (const float*)d_in[13];
  const float* ln_hh1_g = (const float*)d_in[14];
  const float* ln_hh1_b = (const float*)d_in[15];
  const float* ln_ho1_g = (const float*)d_in[16];
  const float* ln_ho1_b = (const float*)d_in[17];
  float* out = (float*)d_out;

  // ws (floats): Gc 6.29M | Wt0 2.10M | Wt1 2.10M | g1pre 262K | R 262K |
  //              Rsums 8K | h 64K | c 64K | bar 16 | xc 64K   ≈ 44.9 MB
  float*  ws    = (float*)d_ws;
  float*  Gc    = ws;
  float*  Wt0   = Gc + (size_t)2*BB*SC*G4;
  float*  Wt1   = Wt0 + (size_t)2*HH*G4;
  float*  g1pre = Wt1 + (size_t)2*HH*G4;
  float*  Rbuf  = g1pre + (size_t)2*BB*G4;
  float2* Rsums = (float2*)(Rbuf + (size_t)2*BB*G4);
  float*  hbuf  = (float*)Rsums + (size_t)2*BB*32*2;
  float*  cbuf  = hbuf + (size_t)2*BB*HH;
  int*    bar   = (int*)(cbuf + (size_t)2*BB*HH);
  float*  xcb   = (float*)(bar + 16);

  // zero h, c, barrier (contiguous region)
  hipMemsetAsync(hbuf, 0, ((size_t)4*BB*HH)*sizeof(float) + 16*sizeof(int), stream);

  // weight transposes (both layers)
  hipLaunchKernelGGL(transpose_f32, dim3(G4/64, HH/64, 2), dim3(256), 0, stream, w_hh0, Wt0);
  hipLaunchKernelGGL(transpose_f32, dim3(G4/64, HH/64, 2), dim3(256), 0, stream, w_hh1, Wt1);

  // ---- layer 0: two 24-step chunks ----
  for (int ch = 0; ch < 2; ++ch) {
    hipLaunchKernelGGL(gemm_ih0, dim3(G4/64, (2*BB*SC)/64), dim3(256), 0, stream,
        x, w_ih0, Gc, ch*SC);
    hipLaunchKernelGGL(ln_rows, dim3(2*BB*SC), dim3(256), 0, stream,
        Gc, ln_ih0_g, ln_ih0_b, BB*SC);
    hipLaunchKernelGGL(persist, dim3(NBLK), dim3(256), 0, stream,
        Wt0, Gc, (size_t)SC*G4, (size_t)G4,
        ln_hh0_g, ln_hh0_b, ln_ho0_g, ln_ho0_b,
        hbuf, cbuf, Rbuf, Rsums,
        xcb, SC, (ch == 1) ? 1 : 0, 1,
        0, (const float*)nullptr, (const float*)nullptr, (float*)nullptr,
        (const float*)nullptr, (const float*)nullptr, bar);
  }

  // ---- layer 1: proj + LN + 48-step scan, all in one persistent kernel ----
  hipLaunchKernelGGL(persist, dim3(NBLK), dim3(256), 0, stream,
      Wt1, g1pre, (size_t)G4, (size_t)0,
      ln_hh1_g, ln_hh1_b, ln_ho1_g, ln_ho1_b,
      hbuf, cbuf, Rbuf, Rsums,
      out, SS, 1, 0,
      1, w_ih1, xcb, g1pre, ln_ih1_g, ln_ih1_b, bar);
}

// Round 5
// 5429.292 us; speedup vs baseline: 2.3881x; 2.3881x over previous
//
#include <hip/hip_runtime.h>
#include <math.h>

#define HH 512
#define BB 64
#define SS 48
#define EE 512
#define G4 2048
#define EPSF 1e-5f
#define AGENT __HIP_MEMORY_SCOPE_AGENT

__device__ __forceinline__ float aload(const float* p) {
  return __hip_atomic_load(p, __ATOMIC_RELAXED, AGENT);
}
__device__ __forceinline__ void astore(float* p, float v) {
  __hip_atomic_store(p, v, __ATOMIC_RELAXED, AGENT);
}

// group barrier: nexp blocks release-add 1 to *c; all spin until count==nexp.
// s_waitcnt(0) first => every wave's outstanding atomics/stores have landed
// at the coherence point before the counter release.
__device__ __forceinline__ void gsync(int* c, int nexp) {
  __builtin_amdgcn_s_waitcnt(0);
  __syncthreads();
  if (threadIdx.x == 0) {
    __hip_atomic_fetch_add(c, 1, __ATOMIC_RELEASE, AGENT);
    int spins = 0;
    while (__hip_atomic_load(c, __ATOMIC_RELAXED, AGENT) < nexp) {
      __builtin_amdgcn_s_sleep(1);
      if (++spins > (1 << 20)) break;   // bailout: avoid harness hang on lost block
    }
    (void)__hip_atomic_load(c, __ATOMIC_ACQUIRE, AGENT);
  }
  __syncthreads();
}

// ======== phase A: layer-0 input projection, full S, both dirs ========
// G0 rows m = d*(B*S) + b*S + tl ; x row b*S + s, s = d ? S-1-tl : tl
__global__ __launch_bounds__(256)
void gemm_ih0(const float* __restrict__ x, const float* __restrict__ w_ih0,
              float* __restrict__ G0) {
  __shared__ float As[16][65];
  __shared__ float Bs[16][65];
  const int m0 = blockIdx.y * 64;
  const int d  = m0 / (BB * SS);
  const float* Wm = w_ih0 + (size_t)d * G4 * EE;
  const int bn = blockIdx.x * 64;
  const int tid = threadIdx.x;
  const int lrow = tid >> 2;
  const int lkk  = (tid & 3) << 2;
  const int tx = tid & 15;
  const int ty = tid >> 4;
  int m  = m0 + lrow;
  int r  = m - d * (BB * SS);
  int b  = r / SS;
  int tl = r - b * SS;
  int s  = d ? (SS - 1 - tl) : tl;
  const float* arow = x + ((size_t)b * SS + s) * EE;

  float acc[4][4] = {};
  for (int k0 = 0; k0 < EE; k0 += 16) {
    float4 av = *(const float4*)(arow + k0 + lkk);
    float4 bv = *(const float4*)(Wm + (size_t)(bn + lrow) * EE + k0 + lkk);
    As[lkk+0][lrow] = av.x; As[lkk+1][lrow] = av.y; As[lkk+2][lrow] = av.z; As[lkk+3][lrow] = av.w;
    Bs[lkk+0][lrow] = bv.x; Bs[lkk+1][lrow] = bv.y; Bs[lkk+2][lrow] = bv.z; Bs[lkk+3][lrow] = bv.w;
    __syncthreads();
    #pragma unroll
    for (int k = 0; k < 16; ++k) {
      float a[4], bbv[4];
      #pragma unroll
      for (int i = 0; i < 4; ++i) a[i] = As[k][ty*4+i];
      #pragma unroll
      for (int j = 0; j < 4; ++j) bbv[j] = Bs[k][tx*4+j];
      #pragma unroll
      for (int i = 0; i < 4; ++i)
        #pragma unroll
        for (int j = 0; j < 4; ++j) acc[i][j] += a[i]*bbv[j];
    }
    __syncthreads();
  }
  for (int i = 0; i < 4; ++i)
    for (int j = 0; j < 4; ++j)
      G0[(size_t)(m0 + ty*4 + i) * G4 + bn + tx*4 + j] = acc[i][j];
}

// ======== in-place LayerNorm on rows of 2048 ========
__global__ __launch_bounds__(256)
void ln_rows(float* __restrict__ X, const float* __restrict__ gamma,
             const float* __restrict__ beta, int rows_per_d) {
  __shared__ float red[8];
  const int row = blockIdx.x;
  const int d = row / rows_per_d;
  float* xr = X + (size_t)row * G4;
  const float* gg = gamma + (size_t)d * G4;
  const float* bb = beta  + (size_t)d * G4;
  float s = 0.f, q = 0.f;
  float v[8];
  #pragma unroll
  for (int it = 0; it < 8; ++it) {
    float xv = xr[threadIdx.x + it*256];
    v[it] = xv; s += xv; q += xv*xv;
  }
  #pragma unroll
  for (int off = 32; off > 0; off >>= 1) { s += __shfl_down(s, off); q += __shfl_down(q, off); }
  int lane = threadIdx.x & 63, wid = threadIdx.x >> 6;
  if (lane == 0) { red[wid] = s; red[4+wid] = q; }
  __syncthreads();
  float ts = red[0]+red[1]+red[2]+red[3];
  float tq = red[4]+red[5]+red[6]+red[7];
  float mu = ts * (1.f/G4);
  float rstd = rsqrtf(tq*(1.f/G4) - mu*mu + EPSF);
  #pragma unroll
  for (int it = 0; it < 8; ++it) {
    int jc = threadIdx.x + it*256;
    xr[jc] = (v[it]-mu)*rstd*gg[jc] + bb[jc];
  }
}

// ======== persistent scan: 256 blocks; weights in VGPRs; gates co-located ========
// block bb: group g = bb&7 (one XCD under round-robin), d = g>>2, bq = g&3,
//           jb = bb>>3 in [0,32). Block owns n-set {jb*16 + q*512 + l}, cells
//           (b in [bq*16,bq*16+16)) x (j in [jb*16, jb*16+16)), c in registers.
// Cross-block: LN stats via fp32 atomicAdd into step-indexed slots; h via sc1.
__global__ __launch_bounds__(256, 1)
void persist2(const float* __restrict__ whh, const float* Gbuf,
              long g_row_stride, long g_t_stride,
              const float* __restrict__ lnhg, const float* __restrict__ lnhb,
              const float* __restrict__ lnog, const float* __restrict__ lnob,
              float* hbuf, float* Rstat, float* Cstat, int* cnt,
              float* fout, int nsteps,
              int mode1, const float* __restrict__ w_ih1,
              const float* __restrict__ xcb, float* g1pre,
              const float* __restrict__ ln_g1, const float* __restrict__ ln_b1,
              int* cnt_pre) {
  __shared__ float hlds[16][512];     // 32 KB
  __shared__ float part[4][16][64];   // 16 KB
  __shared__ float redR[16][64];      //  4 KB

  const int bb = blockIdx.x;
  const int tid = threadIdx.x;
  const int lane = tid & 63;
  const int kq = tid >> 6;

  // ---- mode1 preamble: layer-1 projection + LN(g1pre), grid-synced ----
  if (mode1) {
    const int dp = bb & 1, nbp = bb >> 1;      // 16 n-cols per (dp,nbp)
    const int ns = tid & 3, pb = tid >> 2;     // pb in [0,64)
    const float* xrow = xcb + (size_t)pb * 1024;
    const size_t nbase = (size_t)dp * G4 + (size_t)nbp * 16 + ns;
    const float* w0 = w_ih1 + (nbase + 0)  * 1024;
    const float* w1 = w_ih1 + (nbase + 4)  * 1024;
    const float* w2 = w_ih1 + (nbase + 8)  * 1024;
    const float* w3 = w_ih1 + (nbase + 12) * 1024;
    float a0=0.f, a1=0.f, a2=0.f, a3=0.f;
    for (int k = 0; k < 1024; k += 4) {
      float4 xv = *(const float4*)(xrow + k);
      float4 v0 = *(const float4*)(w0 + k);
      float4 v1 = *(const float4*)(w1 + k);
      float4 v2 = *(const float4*)(w2 + k);
      float4 v3 = *(const float4*)(w3 + k);
      a0 += xv.x*v0.x + xv.y*v0.y + xv.z*v0.z + xv.w*v0.w;
      a1 += xv.x*v1.x + xv.y*v1.y + xv.z*v1.z + xv.w*v1.w;
      a2 += xv.x*v2.x + xv.y*v2.y + xv.z*v2.z + xv.w*v2.w;
      a3 += xv.x*v3.x + xv.y*v3.y + xv.z*v3.z + xv.w*v3.w;
    }
    float* grow = g1pre + ((size_t)dp * BB + pb) * G4 + (size_t)nbp * 16 + ns;
    astore(grow + 0, a0); astore(grow + 4, a1);
    astore(grow + 8, a2); astore(grow + 12, a3);
    gsync(cnt_pre + 0, 256);
    if (bb < 128) {                            // LN row bb
      const int row = bb, ld = row >> 6;
      float* xr = g1pre + (size_t)row * G4;
      const float* gg = ln_g1 + (size_t)ld * G4;
      const float* be = ln_b1 + (size_t)ld * G4;
      __shared__ float sred[16];
      float s = 0.f, q = 0.f;
      float v[8];
      #pragma unroll
      for (int it = 0; it < 8; ++it) {
        float xv = aload(xr + tid + it*256);
        v[it] = xv; s += xv; q += xv*xv;
      }
      #pragma unroll
      for (int off = 32; off > 0; off >>= 1) { s += __shfl_down(s, off); q += __shfl_down(q, off); }
      if (lane == 0) { sred[kq] = s; sred[8+kq] = q; }
      __syncthreads();
      float ts = sred[0]+sred[1]+sred[2]+sred[3];
      float tq = sred[8]+sred[9]+sred[10]+sred[11];
      __syncthreads();
      float mu = ts * (1.f/G4);
      float rstd = rsqrtf(tq*(1.f/G4) - mu*mu + EPSF);
      #pragma unroll
      for (int it = 0; it < 8; ++it) {
        int jc = tid + it*256;
        astore(xr + jc, (v[it]-mu)*rstd*gg[jc] + be[jc]);
      }
    }
    gsync(cnt_pre + 1, 256);
  }

  // ---- decode scan role ----
  const int g  = bb & 7;
  const int d  = g >> 2;
  const int bq = g & 3;
  const int jb = bb >> 3;
  const int q  = lane >> 4, l = lane & 15;
  const int ncol = jb*16 + q*512 + l;

  // ---- weights into registers (once) ----
  float wreg[128];
  {
    const float* wp = whh + ((size_t)d * G4 + ncol) * HH + (size_t)kq * 128;
    #pragma unroll
    for (int i = 0; i < 128; ++i) wreg[i] = wp[i];
  }

  const int bl = tid >> 4, jl = tid & 15;        // cell-role mapping
  const int rowc = d*BB + bq*16 + bl;
  const int jc   = jb*16 + jl;
  float creg = 0.f;

  // ================= scan loop =================
  for (int t = 0; t < nsteps; ++t) {
    // ---- stage h (16 rows x 512) from coherence point ----
    #pragma unroll
    for (int i = 0; i < 32; ++i) {
      int f = i*256 + tid;
      int b = f >> 9, k = f & 511;
      hlds[b][k] = aload(hbuf + ((size_t)(d*BB + bq*16 + b)) * HH + k);
    }
    __syncthreads();
    // ---- GEMV slice: thread = (n=ncol, k-quarter kq), 16 batches ----
    for (int b = 0; b < 16; ++b) {
      const float* hp = &hlds[b][kq*128];
      float acc = 0.f;
      #pragma unroll
      for (int i4 = 0; i4 < 32; ++i4) {
        float4 h4 = *(const float4*)(hp + 4*i4);     // broadcast ds_read_b128
        acc += h4.x*wreg[4*i4+0] + h4.y*wreg[4*i4+1]
             + h4.z*wreg[4*i4+2] + h4.w*wreg[4*i4+3];
      }
      part[kq][b][lane] = acc;
    }
    __syncthreads();
    for (int c0 = tid; c0 < 1024; c0 += 256) {
      int b = c0 >> 6, nl = c0 & 63;
      redR[b][nl] = part[0][b][nl] + part[1][b][nl] + part[2][b][nl] + part[3][b][nl];
    }
    __syncthreads();
    // ---- R-stat partials (this block's 64 n) ----
    #pragma unroll
    for (int bi = 0; bi < 4; ++bi) {
      int b = kq*4 + bi;
      float v = redR[b][lane];
      float s = v, qq = v*v;
      #pragma unroll
      for (int off = 32; off > 0; off >>= 1) { s += __shfl_down(s, off); qq += __shfl_down(qq, off); }
      if (lane == 0) {
        int row = d*BB + bq*16 + b;
        atomicAdd(Rstat + ((size_t)t*128 + row)*2 + 0, s);
        atomicAdd(Rstat + ((size_t)t*128 + row)*2 + 1, qq);
      }
    }
    gsync(cnt + (t*3 + 0)*8 + g, 32);

    // ---- gates + cell update (co-located: R quartet is local) ----
    float ssum = aload(Rstat + ((size_t)t*128 + rowc)*2 + 0);
    float ssq  = aload(Rstat + ((size_t)t*128 + rowc)*2 + 1);
    float mu   = ssum * (1.f/G4);
    float rstd = rsqrtf(ssq*(1.f/G4) - mu*mu + EPSF);
    const float* gr = Gbuf + (size_t)rowc * g_row_stride + (size_t)t * g_t_stride;
    float Ri = redR[bl][jl], Rf = redR[bl][16+jl], Ro = redR[bl][32+jl], Rg = redR[bl][48+jl];
    float gi = aload(gr + jc)        + (Ri-mu)*rstd*lnhg[d*G4 + jc]        + lnhb[d*G4 + jc];
    float gf = aload(gr + HH + jc)   + (Rf-mu)*rstd*lnhg[d*G4 + HH + jc]   + lnhb[d*G4 + HH + jc];
    float go = aload(gr + 2*HH + jc) + (Ro-mu)*rstd*lnhg[d*G4 + 2*HH + jc] + lnhb[d*G4 + 2*HH + jc];
    float gt = aload(gr + 3*HH + jc) + (Rg-mu)*rstd*lnhg[d*G4 + 3*HH + jc] + lnhb[d*G4 + 3*HH + jc];
    float iv = 1.f/(1.f+expf(-gi)), fv = 1.f/(1.f+expf(-gf));
    float ov = 1.f/(1.f+expf(-go)), gv = tanhf(gt);
    creg = fv*creg + iv*gv;
    float cs = creg, cq2 = creg*creg;
    #pragma unroll
    for (int off = 8; off > 0; off >>= 1) {
      cs  += __shfl_down(cs, off, 16);
      cq2 += __shfl_down(cq2, off, 16);
    }
    if (jl == 0) {
      atomicAdd(Cstat + ((size_t)t*128 + rowc)*2 + 0, cs);
      atomicAdd(Cstat + ((size_t)t*128 + rowc)*2 + 1, cq2);
    }
    gsync(cnt + (t*3 + 1)*8 + g, 32);

    float csum = aload(Cstat + ((size_t)t*128 + rowc)*2 + 0);
    float csq  = aload(Cstat + ((size_t)t*128 + rowc)*2 + 1);
    float muc = csum * (1.f/HH);
    float rsc = rsqrtf(csq*(1.f/HH) - muc*muc + EPSF);
    float hv = ov * tanhf((creg - muc)*rsc*lnog[d*HH + jc] + lnob[d*HH + jc]);
    astore(hbuf + (size_t)rowc * HH + jc, hv);
    if (t == nsteps - 1)
      fout[(size_t)(bq*16 + bl) * (2*HH) + (size_t)d * HH + jc] = hv;
    gsync(cnt + (t*3 + 2)*8 + g, 32);
  }
}

extern "C" void kernel_launch(void* const* d_in, const int* in_sizes, int n_in,
                              void* d_out, int out_size, void* d_ws, size_t ws_size,
                              hipStream_t stream) {
  const float* x        = (const float*)d_in[0];
  const float* w_ih0    = (const float*)d_in[2];
  const float* w_hh0    = (const float*)d_in[3];
  const float* ln_ih0_g = (const float*)d_in[4];
  const float* ln_ih0_b = (const float*)d_in[5];
  const float* ln_hh0_g = (const float*)d_in[6];
  const float* ln_hh0_b = (const float*)d_in[7];
  const float* ln_ho0_g = (const float*)d_in[8];
  const float* ln_ho0_b = (const float*)d_in[9];
  const float* w_ih1    = (const float*)d_in[10];
  const float* w_hh1    = (const float*)d_in[11];
  const float* ln_ih1_g = (const float*)d_in[12];
  const float* ln_ih1_b = (const float*)d_in[13];
  const float* ln_hh1_g = (const float*)d_in[14];
  const float* ln_hh1_b = (const float*)d_in[15];
  const float* ln_ho1_g = (const float*)d_in[16];
  const float* ln_ho1_b = (const float*)d_in[17];
  float* out = (float*)d_out;

  // ws (floats): G0 12.58M | g1pre 262K | xcb 64K | hbuf 64K |
  //              Rstat 24.6K | Cstat 24.6K | cnt 2320 ints   ~= 51.8 MB
  float* ws    = (float*)d_ws;
  float* G0    = ws;
  float* g1pre = G0 + (size_t)2*BB*SS*G4;
  float* xcb   = g1pre + (size_t)2*BB*G4;
  float* hbuf  = xcb + (size_t)BB*2*HH;
  float* Rstat = hbuf + (size_t)2*BB*HH;
  float* Cstat = Rstat + (size_t)96*128*2;
  int*   cnt   = (int*)(Cstat + (size_t)96*128*2);   // 96*24 + 16 ints

  // zero hbuf + stats + counters (contiguous)
  hipMemsetAsync(hbuf, 0,
      ((size_t)2*BB*HH + 2*(size_t)96*128*2) * sizeof(float) + (96*24 + 16)*sizeof(int),
      stream);

  // phase A: G0 = LN(x @ w_ih0^T), time-reversal baked in for d=1
  hipLaunchKernelGGL(gemm_ih0, dim3(G4/64, (2*BB*SS)/64), dim3(256), 0, stream,
      x, w_ih0, G0);
  hipLaunchKernelGGL(ln_rows, dim3(2*BB*SS), dim3(256), 0, stream,
      G0, ln_ih0_g, ln_ih0_b, BB*SS);

  // layer 0 scan: rows (d*64+b) stride 48*2048, t stride 2048 -> xcb
  hipLaunchKernelGGL(persist2, dim3(256), dim3(256), 0, stream,
      w_hh0, G0, (long)SS*G4, (long)G4,
      ln_hh0_g, ln_hh0_b, ln_ho0_g, ln_ho0_b,
      hbuf, Rstat, Cstat, cnt, xcb, SS,
      0, (const float*)nullptr, (const float*)nullptr, (float*)nullptr,
      (const float*)nullptr, (const float*)nullptr, (int*)nullptr);

  // reset h for layer 1
  hipMemsetAsync(hbuf, 0, (size_t)2*BB*HH*sizeof(float), stream);

  // layer 1: proj(xcb) + LN in preamble, then 48-step scan (t-stride 0) -> out
  hipLaunchKernelGGL(persist2, dim3(256), dim3(256), 0, stream,
      w_hh1, g1pre, (long)G4, 0L,
      ln_hh1_g, ln_hh1_b, ln_ho1_g, ln_ho1_b,
      hbuf, Rstat + (size_t)SS*128*2, Cstat + (size_t)SS*128*2, cnt + SS*24, out, SS,
      1, w_ih1, xcb, g1pre, ln_ih1_g, ln_ih1_b, cnt + 96*24);
}

// Round 6
// 2880.353 us; speedup vs baseline: 4.5013x; 1.8849x over previous
//
#include <hip/hip_runtime.h>
#include <math.h>

#define HH 512
#define BB 64
#define SS 48
#define EE 512
#define G4 2048
#define EPSF 1e-5f
#define AGENT __HIP_MEMORY_SCOPE_AGENT

__device__ __forceinline__ float aload(const float* p) {
  return __hip_atomic_load(p, __ATOMIC_RELAXED, AGENT);
}
__device__ __forceinline__ void astore(float* p, float v) {
  __hip_atomic_store(p, v, __ATOMIC_RELAXED, AGENT);
}

// monotone group barrier: each block adds 1, waits until counter >= target.
__device__ __forceinline__ void gsync(int* c, int target) {
  __builtin_amdgcn_s_waitcnt(0);
  __syncthreads();
  if (threadIdx.x == 0) {
    __hip_atomic_fetch_add(c, 1, __ATOMIC_RELEASE, AGENT);
    int spins = 0;
    while (__hip_atomic_load(c, __ATOMIC_RELAXED, AGENT) < target) {
      __builtin_amdgcn_s_sleep(1);
      if (++spins > (1 << 22)) break;   // safety bailout
    }
    (void)__hip_atomic_load(c, __ATOMIC_ACQUIRE, AGENT);
  }
  __syncthreads();
}

// ======== phase A: layer-0 input projection, full S, both dirs ========
__global__ __launch_bounds__(256)
void gemm_ih0(const float* __restrict__ x, const float* __restrict__ w_ih0,
              float* __restrict__ G0) {
  __shared__ float As[16][65];
  __shared__ float Bs[16][65];
  const int m0 = blockIdx.y * 64;
  const int d  = m0 / (BB * SS);
  const float* Wm = w_ih0 + (size_t)d * G4 * EE;
  const int bn = blockIdx.x * 64;
  const int tid = threadIdx.x;
  const int lrow = tid >> 2;
  const int lkk  = (tid & 3) << 2;
  const int tx = tid & 15;
  const int ty = tid >> 4;
  int m  = m0 + lrow;
  int r  = m - d * (BB * SS);
  int b  = r / SS;
  int tl = r - b * SS;
  int s  = d ? (SS - 1 - tl) : tl;
  const float* arow = x + ((size_t)b * SS + s) * EE;

  float acc[4][4] = {};
  for (int k0 = 0; k0 < EE; k0 += 16) {
    float4 av = *(const float4*)(arow + k0 + lkk);
    float4 bv = *(const float4*)(Wm + (size_t)(bn + lrow) * EE + k0 + lkk);
    As[lkk+0][lrow] = av.x; As[lkk+1][lrow] = av.y; As[lkk+2][lrow] = av.z; As[lkk+3][lrow] = av.w;
    Bs[lkk+0][lrow] = bv.x; Bs[lkk+1][lrow] = bv.y; Bs[lkk+2][lrow] = bv.z; Bs[lkk+3][lrow] = bv.w;
    __syncthreads();
    #pragma unroll
    for (int k = 0; k < 16; ++k) {
      float a[4], bbv[4];
      #pragma unroll
      for (int i = 0; i < 4; ++i) a[i] = As[k][ty*4+i];
      #pragma unroll
      for (int j = 0; j < 4; ++j) bbv[j] = Bs[k][tx*4+j];
      #pragma unroll
      for (int i = 0; i < 4; ++i)
        #pragma unroll
        for (int j = 0; j < 4; ++j) acc[i][j] += a[i]*bbv[j];
    }
    __syncthreads();
  }
  for (int i = 0; i < 4; ++i)
    for (int j = 0; j < 4; ++j)
      G0[(size_t)(m0 + ty*4 + i) * G4 + bn + tx*4 + j] = acc[i][j];
}

// ======== in-place LayerNorm on rows of 2048 ========
__global__ __launch_bounds__(256)
void ln_rows(float* __restrict__ X, const float* __restrict__ gamma,
             const float* __restrict__ beta, int rows_per_d) {
  __shared__ float red[8];
  const int row = blockIdx.x;
  const int d = row / rows_per_d;
  float* xr = X + (size_t)row * G4;
  const float* gg = gamma + (size_t)d * G4;
  const float* bb = beta  + (size_t)d * G4;
  float s = 0.f, q = 0.f;
  float v[8];
  #pragma unroll
  for (int it = 0; it < 8; ++it) {
    float xv = xr[threadIdx.x + it*256];
    v[it] = xv; s += xv; q += xv*xv;
  }
  #pragma unroll
  for (int off = 32; off > 0; off >>= 1) { s += __shfl_down(s, off); q += __shfl_down(q, off); }
  int lane = threadIdx.x & 63, wid = threadIdx.x >> 6;
  if (lane == 0) { red[wid] = s; red[4+wid] = q; }
  __syncthreads();
  float ts = red[0]+red[1]+red[2]+red[3];
  float tq = red[4]+red[5]+red[6]+red[7];
  float mu = ts * (1.f/G4);
  float rstd = rsqrtf(tq*(1.f/G4) - mu*mu + EPSF);
  #pragma unroll
  for (int it = 0; it < 8; ++it) {
    int jc = threadIdx.x + it*256;
    xr[jc] = (v[it]-mu)*rstd*gg[jc] + bb[jc];
  }
}

// ======== persistent scan: 256 blocks x 512 threads ========
// group g = bb&7 = (d, bq); jb = bb>>3 in [0,32). Block owns n-cols
// {jb*16 + q*512 + l} (64 cols), batches bq*16..+16. Wave = k-eighth (wreg[64]).
// Cross-block: (c,o) published bypass-L2; LN stats as per-(row,jb) partials.
__global__ __launch_bounds__(512, 2)
void persist3(const float* __restrict__ whh, const float* __restrict__ Gbuf,
              long g_row_stride, long g_t_stride,
              const float* __restrict__ lnhg, const float* __restrict__ lnhb,
              const float* __restrict__ lnog, const float* __restrict__ lnob,
              float* cbuf, float* obuf, float* Rpart, float* Cpart, int* cnt,
              float* fout, int nsteps,
              int mode1, const float* __restrict__ w_ih1,
              const float* __restrict__ xcb, float* g1pre,
              const float* __restrict__ ln_g1, const float* __restrict__ ln_b1,
              int* cnt_pre) {
  __shared__ float hlds[16][512];     // 32 KB
  __shared__ float part[8][8][64];    // 16 KB (b-halves)
  __shared__ float redR[16][64];      //  4 KB
  __shared__ float bcR[16][2];
  __shared__ float bcC[16][2];
  __shared__ float sred[16];

  const int bb = blockIdx.x;
  const int tid = threadIdx.x;

  // ---- mode1 preamble: layer-1 projection + LN(g1pre) ----
  if (mode1) {
    const int dp = bb & 1, nbp = bb >> 1;      // nbp in [0,128)
    const int pb = tid >> 3, ns = tid & 7;     // pb in [0,64)
    const int col0 = nbp*16 + ns, col1 = col0 + 8;
    const float* xrow = xcb + (size_t)pb * 1024;
    const float* w0 = w_ih1 + ((size_t)dp*G4 + col0) * 1024;
    const float* w1 = w_ih1 + ((size_t)dp*G4 + col1) * 1024;
    float a0 = 0.f, a1 = 0.f;
    for (int k = 0; k < 1024; k += 4) {
      float4 xv = *(const float4*)(xrow + k);
      float4 v0 = *(const float4*)(w0 + k);
      float4 v1 = *(const float4*)(w1 + k);
      a0 += xv.x*v0.x + xv.y*v0.y + xv.z*v0.z + xv.w*v0.w;
      a1 += xv.x*v1.x + xv.y*v1.y + xv.z*v1.z + xv.w*v1.w;
    }
    float* grow = g1pre + ((size_t)dp*BB + pb) * G4;
    astore(grow + col0, a0);
    astore(grow + col1, a1);
    gsync(cnt_pre + 0, 256);
    if (bb < 128) {
      const int ld = bb >> 6;
      float* xr = g1pre + (size_t)bb * G4;
      const float* gg = ln_g1 + (size_t)ld * G4;
      const float* be = ln_b1 + (size_t)ld * G4;
      float v[4]; float s = 0.f, q = 0.f;
      #pragma unroll
      for (int i = 0; i < 4; ++i) {
        float xv = aload(xr + i*512 + tid);
        v[i] = xv; s += xv; q += xv*xv;
      }
      #pragma unroll
      for (int off = 32; off > 0; off >>= 1) { s += __shfl_down(s, off); q += __shfl_down(q, off); }
      const int wv = tid >> 6;
      if ((tid & 63) == 0) { sred[wv] = s; sred[8+wv] = q; }
      __syncthreads();
      float ts = 0.f, tq = 0.f;
      #pragma unroll
      for (int i = 0; i < 8; ++i) { ts += sred[i]; tq += sred[8+i]; }
      float mu = ts * (1.f/G4);
      float rstd = rsqrtf(tq*(1.f/G4) - mu*mu + EPSF);
      #pragma unroll
      for (int i = 0; i < 4; ++i) {
        int jcx = i*512 + tid;
        astore(xr + jcx, (v[i]-mu)*rstd*gg[jcx] + be[jcx]);
      }
    }
    gsync(cnt_pre + 16, 256);
  }

  // ---- scan role decode ----
  const int g  = bb & 7;
  const int d  = g >> 2;
  const int bq = g & 3;
  const int jb = bb >> 3;
  const int rowbase = d*BB + bq*16;
  const int ke = tid >> 6, nl = tid & 63;     // wave = ke, lane = nl
  const int qgate = nl >> 4, lcol = nl & 15;
  const int ncol = jb*16 + qgate*512 + lcol;

  float wreg[64];
  {
    const float* wp = whh + ((size_t)d*G4 + ncol)*HH + (size_t)ke*64;
    #pragma unroll
    for (int i = 0; i < 64; ++i) wreg[i] = wp[i];
  }

  const int bl = tid >> 4, jl = tid & 15;     // update role (tid<256)
  const int rowc = rowbase + bl;
  const int jc = jb*16 + jl;
  const float* lnhg_d = lnhg + (size_t)d*G4;
  const float* lnhb_d = lnhb + (size_t)d*G4;
  const float ogv = lnog[(size_t)d*HH + tid]; // k = tid in staging
  const float obv = lnob[(size_t)d*HH + tid];
  float creg = 0.f;

  const int row16 = tid >> 5, j32 = tid & 31;
  int* cA = cnt + g*16;
  int* cB = cnt + 128 + g*16;

  for (int t = 0; t < nsteps; ++t) {
    // ---- staging: h(t-1) = o * tanh(LN(c)) ----
    float cv[16], ovv[16];
    #pragma unroll
    for (int i = 0; i < 16; ++i) {
      cv[i]  = aload(cbuf + (size_t)(rowbase + i)*512 + tid);
      ovv[i] = aload(obuf + (size_t)(rowbase + i)*512 + tid);
    }
    {
      float s = aload(Cpart + ((size_t)(rowbase+row16)*32 + j32)*2 + 0);
      float q = aload(Cpart + ((size_t)(rowbase+row16)*32 + j32)*2 + 1);
      #pragma unroll
      for (int off = 16; off > 0; off >>= 1) { s += __shfl_down(s, off, 32); q += __shfl_down(q, off, 32); }
      if (j32 == 0) {
        float mu = s * (1.f/HH);
        bcC[row16][0] = mu;
        bcC[row16][1] = rsqrtf(q*(1.f/HH) - mu*mu + EPSF);
      }
    }
    __syncthreads();
    #pragma unroll
    for (int i = 0; i < 16; ++i)
      hlds[i][tid] = ovv[i] * tanhf((cv[i] - bcC[i][0]) * bcC[i][1] * ogv + obv);
    __syncthreads();

    // ---- GEMV in two b-halves (part LDS halved) ----
    #pragma unroll
    for (int half = 0; half < 2; ++half) {
      #pragma unroll
      for (int b = 0; b < 8; ++b) {
        const float* hp = &hlds[half*8 + b][ke*64];
        float acc = 0.f;
        #pragma unroll
        for (int i4 = 0; i4 < 16; ++i4) {
          float4 h4 = *(const float4*)(hp + 4*i4);
          acc += h4.x*wreg[4*i4+0] + h4.y*wreg[4*i4+1]
               + h4.z*wreg[4*i4+2] + h4.w*wreg[4*i4+3];
        }
        part[ke][b][nl] = acc;
      }
      __syncthreads();
      {
        int b = tid >> 6, n2 = tid & 63;    // 512 = 8 b x 64 n
        float r = 0.f;
        #pragma unroll
        for (int k8 = 0; k8 < 8; ++k8) r += part[k8][b][n2];
        redR[half*8 + b][n2] = r;
      }
      __syncthreads();
    }
    // ---- R LN partials for this block's 64 cols ----
    {
      float v1 = redR[row16][j32], v2 = redR[row16][j32+32];
      float s = v1 + v2, q = v1*v1 + v2*v2;
      #pragma unroll
      for (int off = 16; off > 0; off >>= 1) { s += __shfl_down(s, off, 32); q += __shfl_down(q, off, 32); }
      if (j32 == 0) {
        astore(Rpart + ((size_t)(rowbase+row16)*32 + jb)*2 + 0, s);
        astore(Rpart + ((size_t)(rowbase+row16)*32 + jb)*2 + 1, q);
      }
    }
    gsync(cA, 32*(t+1));

    // ---- reduce Rpart -> (mu, rstd) per row ----
    {
      float s = aload(Rpart + ((size_t)(rowbase+row16)*32 + j32)*2 + 0);
      float q = aload(Rpart + ((size_t)(rowbase+row16)*32 + j32)*2 + 1);
      #pragma unroll
      for (int off = 16; off > 0; off >>= 1) { s += __shfl_down(s, off, 32); q += __shfl_down(q, off, 32); }
      if (j32 == 0) {
        float mu = s * (1.f/G4);
        bcR[row16][0] = mu;
        bcR[row16][1] = rsqrtf(q*(1.f/G4) - mu*mu + EPSF);
      }
    }
    __syncthreads();

    // ---- gates + cell update + publish (tid<256: 16b x 16j tile) ----
    if (tid < 256) {
      float mu = bcR[bl][0], rstd = bcR[bl][1];
      const float* gr = Gbuf + (size_t)rowc * g_row_stride + (size_t)t * g_t_stride;
      float gi = gr[jc]        + (redR[bl][jl]    - mu)*rstd*lnhg_d[jc]        + lnhb_d[jc];
      float gf = gr[HH+jc]     + (redR[bl][16+jl] - mu)*rstd*lnhg_d[HH+jc]     + lnhb_d[HH+jc];
      float go = gr[2*HH+jc]   + (redR[bl][32+jl] - mu)*rstd*lnhg_d[2*HH+jc]   + lnhb_d[2*HH+jc];
      float gt = gr[3*HH+jc]   + (redR[bl][48+jl] - mu)*rstd*lnhg_d[3*HH+jc]   + lnhb_d[3*HH+jc];
      float iv = 1.f/(1.f+expf(-gi)), fv = 1.f/(1.f+expf(-gf));
      float ov = 1.f/(1.f+expf(-go)), gv = tanhf(gt);
      creg = fv*creg + iv*gv;
      float cs = creg, cq = creg*creg;
      #pragma unroll
      for (int off = 8; off > 0; off >>= 1) { cs += __shfl_down(cs, off, 16); cq += __shfl_down(cq, off, 16); }
      if (jl == 0) {
        astore(Cpart + ((size_t)rowc*32 + jb)*2 + 0, cs);
        astore(Cpart + ((size_t)rowc*32 + jb)*2 + 1, cq);
      }
      astore(cbuf + (size_t)rowc*512 + jc, creg);
      astore(obuf + (size_t)rowc*512 + jc, ov);
    }
    gsync(cB, 32*(t+1));
  }

  // ---- final h -> output (jb==0 block of each group writes its 16 rows) ----
  {
    float cv[16], ovv[16];
    #pragma unroll
    for (int i = 0; i < 16; ++i) {
      cv[i]  = aload(cbuf + (size_t)(rowbase + i)*512 + tid);
      ovv[i] = aload(obuf + (size_t)(rowbase + i)*512 + tid);
    }
    float s = aload(Cpart + ((size_t)(rowbase+row16)*32 + j32)*2 + 0);
    float q = aload(Cpart + ((size_t)(rowbase+row16)*32 + j32)*2 + 1);
    #pragma unroll
    for (int off = 16; off > 0; off >>= 1) { s += __shfl_down(s, off, 32); q += __shfl_down(q, off, 32); }
    if (j32 == 0) {
      float mu = s * (1.f/HH);
      bcC[row16][0] = mu;
      bcC[row16][1] = rsqrtf(q*(1.f/HH) - mu*mu + EPSF);
    }
    __syncthreads();
    if (jb == 0) {
      #pragma unroll
      for (int i = 0; i < 16; ++i) {
        float h = ovv[i] * tanhf((cv[i] - bcC[i][0]) * bcC[i][1] * ogv + obv);
        fout[(size_t)(bq*16 + i) * 1024 + (size_t)d*512 + tid] = h;
      }
    }
  }
}

extern "C" void kernel_launch(void* const* d_in, const int* in_sizes, int n_in,
                              void* d_out, int out_size, void* d_ws, size_t ws_size,
                              hipStream_t stream) {
  const float* x        = (const float*)d_in[0];
  const float* w_ih0    = (const float*)d_in[2];
  const float* w_hh0    = (const float*)d_in[3];
  const float* ln_ih0_g = (const float*)d_in[4];
  const float* ln_ih0_b = (const float*)d_in[5];
  const float* ln_hh0_g = (const float*)d_in[6];
  const float* ln_hh0_b = (const float*)d_in[7];
  const float* ln_ho0_g = (const float*)d_in[8];
  const float* ln_ho0_b = (const float*)d_in[9];
  const float* w_ih1    = (const float*)d_in[10];
  const float* w_hh1    = (const float*)d_in[11];
  const float* ln_ih1_g = (const float*)d_in[12];
  const float* ln_ih1_b = (const float*)d_in[13];
  const float* ln_hh1_g = (const float*)d_in[14];
  const float* ln_hh1_b = (const float*)d_in[15];
  const float* ln_ho1_g = (const float*)d_in[16];
  const float* ln_ho1_b = (const float*)d_in[17];
  float* out = (float*)d_out;

  // ws (floats): G0 12.58M | g1pre 262K | xcb 64K | Rpart 8K |
  //   [zero region: Cpart 8K | cbuf 64K | obuf 64K | cnt 1024 ints]  ~= 52.2 MB
  float* G0    = (float*)d_ws;
  float* g1pre = G0 + (size_t)2*BB*SS*G4;
  float* xcb   = g1pre + (size_t)2*BB*G4;
  float* Rpart = xcb + (size_t)BB*1024;
  float* Cpart = Rpart + (size_t)128*32*2;
  float* cbuf  = Cpart + (size_t)128*32*2;
  float* obuf  = cbuf + (size_t)128*512;
  int*   cnt   = (int*)(obuf + (size_t)128*512);
  // counters: L0 scan [0..256), L1 scan [256..512), preamble [512..544)

  // zero Cpart + cbuf + obuf + all counters
  hipMemsetAsync(Cpart, 0, ((size_t)128*32*2 + 2*(size_t)128*512)*sizeof(float)
                           + 1024*sizeof(int), stream);

  // phase A: G0 = LN(x @ w_ih0^T), time-reversal baked in for d=1
  hipLaunchKernelGGL(gemm_ih0, dim3(G4/64, (2*BB*SS)/64), dim3(256), 0, stream,
      x, w_ih0, G0);
  hipLaunchKernelGGL(ln_rows, dim3(2*BB*SS), dim3(256), 0, stream,
      G0, ln_ih0_g, ln_ih0_b, BB*SS);

  // layer 0 scan -> xcb
  hipLaunchKernelGGL(persist3, dim3(256), dim3(512), 0, stream,
      w_hh0, G0, (long)SS*G4, (long)G4,
      ln_hh0_g, ln_hh0_b, ln_ho0_g, ln_ho0_b,
      cbuf, obuf, Rpart, Cpart, cnt, xcb, SS,
      0, (const float*)nullptr, (const float*)nullptr, (float*)nullptr,
      (const float*)nullptr, (const float*)nullptr, (int*)nullptr);

  // re-zero Cpart + cbuf + obuf for layer 1 (counters untouched: L1 has own region)
  hipMemsetAsync(Cpart, 0, ((size_t)128*32*2 + 2*(size_t)128*512)*sizeof(float), stream);

  // layer 1: projection + LN in preamble, then scan (t-stride 0) -> out
  hipLaunchKernelGGL(persist3, dim3(256), dim3(512), 0, stream,
      w_hh1, g1pre, (long)G4, 0L,
      ln_hh1_g, ln_hh1_b, ln_ho1_g, ln_ho1_b,
      cbuf, obuf, Rpart, Cpart, cnt + 256, out, SS,
      1, w_ih1, xcb, g1pre, ln_ih1_g, ln_ih1_b, cnt + 512);
}

// Round 7
// 2828.317 us; speedup vs baseline: 4.5841x; 1.0184x over previous
//
#include <hip/hip_runtime.h>
#include <math.h>

#define HH 512
#define BB 64
#define SS 48
#define EE 512
#define G4 2048
#define EPSF 1e-5f
#define AGENT __HIP_MEMORY_SCOPE_AGENT

__device__ __forceinline__ float aload(const float* p) {
  return __hip_atomic_load(p, __ATOMIC_RELAXED, AGENT);
}
__device__ __forceinline__ void astore(float* p, float v) {
  __hip_atomic_store(p, v, __ATOMIC_RELAXED, AGENT);
}

// monotone group barrier: each block adds 1, waits until counter >= target.
__device__ __forceinline__ void gsync(int* c, int target) {
  __builtin_amdgcn_s_waitcnt(0);
  __syncthreads();
  if (threadIdx.x == 0) {
    __hip_atomic_fetch_add(c, 1, __ATOMIC_RELEASE, AGENT);
    int spins = 0;
    while (__hip_atomic_load(c, __ATOMIC_RELAXED, AGENT) < target) {
      __builtin_amdgcn_s_sleep(1);
      if (++spins > (1 << 22)) break;   // safety bailout
    }
    (void)__hip_atomic_load(c, __ATOMIC_ACQUIRE, AGENT);
  }
  __syncthreads();
}

// ======== phase A: layer-0 input projection, full S, both dirs ========
__global__ __launch_bounds__(256)
void gemm_ih0(const float* __restrict__ x, const float* __restrict__ w_ih0,
              float* __restrict__ G0) {
  __shared__ float As[16][65];
  __shared__ float Bs[16][65];
  const int m0 = blockIdx.y * 64;
  const int d  = m0 / (BB * SS);
  const float* Wm = w_ih0 + (size_t)d * G4 * EE;
  const int bn = blockIdx.x * 64;
  const int tid = threadIdx.x;
  const int lrow = tid >> 2;
  const int lkk  = (tid & 3) << 2;
  const int tx = tid & 15;
  const int ty = tid >> 4;
  int m  = m0 + lrow;
  int r  = m - d * (BB * SS);
  int b  = r / SS;
  int tl = r - b * SS;
  int s  = d ? (SS - 1 - tl) : tl;
  const float* arow = x + ((size_t)b * SS + s) * EE;

  float acc[4][4] = {};
  for (int k0 = 0; k0 < EE; k0 += 16) {
    float4 av = *(const float4*)(arow + k0 + lkk);
    float4 bv = *(const float4*)(Wm + (size_t)(bn + lrow) * EE + k0 + lkk);
    As[lkk+0][lrow] = av.x; As[lkk+1][lrow] = av.y; As[lkk+2][lrow] = av.z; As[lkk+3][lrow] = av.w;
    Bs[lkk+0][lrow] = bv.x; Bs[lkk+1][lrow] = bv.y; Bs[lkk+2][lrow] = bv.z; Bs[lkk+3][lrow] = bv.w;
    __syncthreads();
    #pragma unroll
    for (int k = 0; k < 16; ++k) {
      float a[4], bbv[4];
      #pragma unroll
      for (int i = 0; i < 4; ++i) a[i] = As[k][ty*4+i];
      #pragma unroll
      for (int j = 0; j < 4; ++j) bbv[j] = Bs[k][tx*4+j];
      #pragma unroll
      for (int i = 0; i < 4; ++i)
        #pragma unroll
        for (int j = 0; j < 4; ++j) acc[i][j] += a[i]*bbv[j];
    }
    __syncthreads();
  }
  for (int i = 0; i < 4; ++i)
    for (int j = 0; j < 4; ++j)
      G0[(size_t)(m0 + ty*4 + i) * G4 + bn + tx*4 + j] = acc[i][j];
}

// ======== in-place LayerNorm on rows of 2048 ========
__global__ __launch_bounds__(256)
void ln_rows(float* __restrict__ X, const float* __restrict__ gamma,
             const float* __restrict__ beta, int rows_per_d) {
  __shared__ float red[8];
  const int row = blockIdx.x;
  const int d = row / rows_per_d;
  float* xr = X + (size_t)row * G4;
  const float* gg = gamma + (size_t)d * G4;
  const float* bb = beta  + (size_t)d * G4;
  float s = 0.f, q = 0.f;
  float v[8];
  #pragma unroll
  for (int it = 0; it < 8; ++it) {
    float xv = xr[threadIdx.x + it*256];
    v[it] = xv; s += xv; q += xv*xv;
  }
  #pragma unroll
  for (int off = 32; off > 0; off >>= 1) { s += __shfl_down(s, off); q += __shfl_down(q, off); }
  int lane = threadIdx.x & 63, wid = threadIdx.x >> 6;
  if (lane == 0) { red[wid] = s; red[4+wid] = q; }
  __syncthreads();
  float ts = red[0]+red[1]+red[2]+red[3];
  float tq = red[4]+red[5]+red[6]+red[7];
  float mu = ts * (1.f/G4);
  float rstd = rsqrtf(tq*(1.f/G4) - mu*mu + EPSF);
  #pragma unroll
  for (int it = 0; it < 8; ++it) {
    int jc = threadIdx.x + it*256;
    xr[jc] = (v[it]-mu)*rstd*gg[jc] + bb[jc];
  }
}

// ======== persistent scan: 256 blocks x 1024 threads, 1 block/CU ========
// group g = bb&7 = (d, bq); jb = bb>>3 in [0,32). Block owns 64 n-cols
// {jb*16 + q*512 + l}, batches bq*16..+16. Wave ke = k-slice of 32 (wreg[32]).
// LDS ~103 KB forces exactly 1 block per CU (160 KB limit).
__global__ __launch_bounds__(1024, 4)
void persist4(const float* __restrict__ whh, const float* __restrict__ Gbuf,
              long g_row_stride, long g_t_stride,
              const float* __restrict__ lnhg, const float* __restrict__ lnhb,
              const float* __restrict__ lnog, const float* __restrict__ lnob,
              float* cbuf, float* obuf, float* Rpart, float* Cpart, int* cnt,
              float* fout, int nsteps,
              int mode1, const float* __restrict__ w_ih1,
              const float* __restrict__ xcb, float* g1pre,
              const float* __restrict__ ln_g1, const float* __restrict__ ln_b1,
              int* cnt_pre) {
  __shared__ float hlds[16][1024];    // 64 KB (cols 0..511 used; width pads LDS)
  __shared__ float part[16][8][64];   // 32 KB
  __shared__ float redR[16][64];      //  4 KB
  __shared__ float bcR[16][2];
  __shared__ float bcC[16][2];
  __shared__ float sred[32];

  const int bb = blockIdx.x;
  const int tid = threadIdx.x;

  // ---- mode1 preamble: layer-1 projection + LN(g1pre) ----
  if (mode1) {
    const int dp = bb & 1, nbp = bb >> 1;      // nbp in [0,128)
    const int pb = tid >> 4, ns = tid & 15;    // pb in [0,64)
    const int col = nbp*16 + ns;
    const float* xrow = xcb + (size_t)pb * 1024;
    const float* w = w_ih1 + ((size_t)dp*G4 + col) * 1024;
    float a = 0.f;
    for (int k = 0; k < 1024; k += 4) {
      float4 xv = *(const float4*)(xrow + k);
      float4 wv = *(const float4*)(w + k);
      a += xv.x*wv.x + xv.y*wv.y + xv.z*wv.z + xv.w*wv.w;
    }
    astore(g1pre + ((size_t)dp*BB + pb) * G4 + col, a);
    gsync(cnt_pre + 0, 256);
    if (bb < 128) {
      const int ld = bb >> 6;
      float* xr = g1pre + (size_t)bb * G4;
      const float* gg = ln_g1 + (size_t)ld * G4;
      const float* be = ln_b1 + (size_t)ld * G4;
      float v0 = aload(xr + tid), v1 = aload(xr + tid + 1024);
      float s = v0 + v1, q = v0*v0 + v1*v1;
      #pragma unroll
      for (int off = 32; off > 0; off >>= 1) { s += __shfl_down(s, off); q += __shfl_down(q, off); }
      const int wv2 = tid >> 6;
      if ((tid & 63) == 0) { sred[wv2] = s; sred[16+wv2] = q; }
      __syncthreads();
      float ts = 0.f, tq = 0.f;
      #pragma unroll
      for (int i = 0; i < 16; ++i) { ts += sred[i]; tq += sred[16+i]; }
      float mu = ts * (1.f/G4);
      float rstd = rsqrtf(tq*(1.f/G4) - mu*mu + EPSF);
      astore(xr + tid,        (v0-mu)*rstd*gg[tid]      + be[tid]);
      astore(xr + tid + 1024, (v1-mu)*rstd*gg[tid+1024] + be[tid+1024]);
    }
    gsync(cnt_pre + 16, 256);
  }

  // ---- scan role decode ----
  const int g  = bb & 7;
  const int d  = g >> 2;
  const int bq = g & 3;
  const int jb = bb >> 3;
  const int rowbase = d*BB + bq*16;
  const int ke = tid >> 6, nl = tid & 63;       // wave = k-slice, lane = col
  const int ncol = jb*16 + (nl>>4)*512 + (nl&15);

  float wreg[32];
  {
    const float* wp = whh + ((size_t)d*G4 + ncol)*HH + (size_t)ke*32;
    #pragma unroll
    for (int i = 0; i < 32; ++i) wreg[i] = wp[i];
  }

  const int bl = tid >> 4, jl = tid & 15;       // update role (tid<256)
  const int rowc = rowbase + bl;
  const int jc = jb*16 + jl;
  const float* lnhg_d = lnhg + (size_t)d*G4;
  const float* lnhb_d = lnhb + (size_t)d*G4;
  const int scol = tid & 511, srh = tid >> 9;   // staging col, row-half
  const float ogv = lnog[(size_t)d*HH + scol];
  const float obv = lnob[(size_t)d*HH + scol];
  const int row16 = tid >> 5, j32 = tid & 31;   // reduce roles (tid<512)
  float creg = 0.f;
  int* cA = cnt + g*16;
  int* cB = cnt + 128 + g*16;

  for (int t = 0; t < nsteps; ++t) {
    // ---- staging: h(t-1) = o * tanh(LN(c)); 8 rows x 512 per half-block ----
    float cv[8], ovv[8];
    #pragma unroll
    for (int i = 0; i < 8; ++i) {
      int row = i*2 + srh;
      cv[i]  = aload(cbuf + (size_t)(rowbase + row)*512 + scol);
      ovv[i] = aload(obuf + (size_t)(rowbase + row)*512 + scol);
    }
    if (tid < 512) {
      float s = aload(Cpart + ((size_t)(rowbase+row16)*32 + j32)*2 + 0);
      float q = aload(Cpart + ((size_t)(rowbase+row16)*32 + j32)*2 + 1);
      #pragma unroll
      for (int off = 16; off > 0; off >>= 1) { s += __shfl_down(s, off, 32); q += __shfl_down(q, off, 32); }
      if (j32 == 0) {
        float mu = s * (1.f/HH);
        bcC[row16][0] = mu;
        bcC[row16][1] = rsqrtf(q*(1.f/HH) - mu*mu + EPSF);
      }
    }
    __syncthreads();
    #pragma unroll
    for (int i = 0; i < 8; ++i) {
      int row = i*2 + srh;
      hlds[row][scol] = ovv[i] * tanhf((cv[i] - bcC[row][0]) * bcC[row][1] * ogv + obv);
    }
    __syncthreads();

    // ---- GEMV in two b-halves ----
    #pragma unroll
    for (int half = 0; half < 2; ++half) {
      #pragma unroll
      for (int b = 0; b < 8; ++b) {
        const float* hp = &hlds[half*8 + b][ke*32];
        float acc = 0.f;
        #pragma unroll
        for (int i4 = 0; i4 < 8; ++i4) {
          float4 h4 = *(const float4*)(hp + 4*i4);
          acc += h4.x*wreg[4*i4+0] + h4.y*wreg[4*i4+1]
               + h4.z*wreg[4*i4+2] + h4.w*wreg[4*i4+3];
        }
        part[ke][b][nl] = acc;
      }
      __syncthreads();
      if (tid < 512) {
        int b = tid >> 6, n2 = tid & 63;
        float r = 0.f;
        #pragma unroll
        for (int k16 = 0; k16 < 16; ++k16) r += part[k16][b][n2];
        redR[half*8 + b][n2] = r;
      }
      __syncthreads();
    }
    // ---- R LN partials for this block's 64 cols ----
    if (tid < 512) {
      float v1 = redR[row16][j32], v2 = redR[row16][j32+32];
      float s = v1 + v2, q = v1*v1 + v2*v2;
      #pragma unroll
      for (int off = 16; off > 0; off >>= 1) { s += __shfl_down(s, off, 32); q += __shfl_down(q, off, 32); }
      if (j32 == 0) {
        astore(Rpart + ((size_t)(rowbase+row16)*32 + jb)*2 + 0, s);
        astore(Rpart + ((size_t)(rowbase+row16)*32 + jb)*2 + 1, q);
      }
    }
    // ---- prefetch gate row (overlaps barrier wait) ----
    float pg0 = 0.f, pg1 = 0.f, pg2 = 0.f, pg3 = 0.f;
    if (tid < 256) {
      const float* gr = Gbuf + (size_t)rowc * g_row_stride + (size_t)t * g_t_stride;
      pg0 = gr[jc]; pg1 = gr[HH+jc]; pg2 = gr[2*HH+jc]; pg3 = gr[3*HH+jc];
    }
    gsync(cA, 32*(t+1));

    // ---- reduce Rpart -> (mu, rstd) per row ----
    if (tid < 512) {
      float s = aload(Rpart + ((size_t)(rowbase+row16)*32 + j32)*2 + 0);
      float q = aload(Rpart + ((size_t)(rowbase+row16)*32 + j32)*2 + 1);
      #pragma unroll
      for (int off = 16; off > 0; off >>= 1) { s += __shfl_down(s, off, 32); q += __shfl_down(q, off, 32); }
      if (j32 == 0) {
        float mu = s * (1.f/G4);
        bcR[row16][0] = mu;
        bcR[row16][1] = rsqrtf(q*(1.f/G4) - mu*mu + EPSF);
      }
    }
    __syncthreads();

    // ---- gates + cell update + publish (tid<256: 16b x 16j tile) ----
    if (tid < 256) {
      float mu = bcR[bl][0], rstd = bcR[bl][1];
      float gi = pg0 + (redR[bl][jl]    - mu)*rstd*lnhg_d[jc]        + lnhb_d[jc];
      float gf = pg1 + (redR[bl][16+jl] - mu)*rstd*lnhg_d[HH+jc]     + lnhb_d[HH+jc];
      float go = pg2 + (redR[bl][32+jl] - mu)*rstd*lnhg_d[2*HH+jc]   + lnhb_d[2*HH+jc];
      float gt = pg3 + (redR[bl][48+jl] - mu)*rstd*lnhg_d[3*HH+jc]   + lnhb_d[3*HH+jc];
      float iv = 1.f/(1.f+expf(-gi)), fv = 1.f/(1.f+expf(-gf));
      float ov = 1.f/(1.f+expf(-go)), gv = tanhf(gt);
      creg = fv*creg + iv*gv;
      float cs = creg, cq = creg*creg;
      #pragma unroll
      for (int off = 8; off > 0; off >>= 1) { cs += __shfl_down(cs, off, 16); cq += __shfl_down(cq, off, 16); }
      if (jl == 0) {
        astore(Cpart + ((size_t)rowc*32 + jb)*2 + 0, cs);
        astore(Cpart + ((size_t)rowc*32 + jb)*2 + 1, cq);
      }
      astore(cbuf + (size_t)rowc*512 + jc, creg);
      astore(obuf + (size_t)rowc*512 + jc, ov);
    }
    gsync(cB, 32*(t+1));
  }

  // ---- final h -> output (jb==0 block of each group writes its 16 rows) ----
  {
    float cv[8], ovv[8];
    #pragma unroll
    for (int i = 0; i < 8; ++i) {
      int row = i*2 + srh;
      cv[i]  = aload(cbuf + (size_t)(rowbase + row)*512 + scol);
      ovv[i] = aload(obuf + (size_t)(rowbase + row)*512 + scol);
    }
    if (tid < 512) {
      float s = aload(Cpart + ((size_t)(rowbase+row16)*32 + j32)*2 + 0);
      float q = aload(Cpart + ((size_t)(rowbase+row16)*32 + j32)*2 + 1);
      #pragma unroll
      for (int off = 16; off > 0; off >>= 1) { s += __shfl_down(s, off, 32); q += __shfl_down(q, off, 32); }
      if (j32 == 0) {
        float mu = s * (1.f/HH);
        bcC[row16][0] = mu;
        bcC[row16][1] = rsqrtf(q*(1.f/HH) - mu*mu + EPSF);
      }
    }
    __syncthreads();
    if (jb == 0) {
      #pragma unroll
      for (int i = 0; i < 8; ++i) {
        int row = i*2 + srh;
        float h = ovv[i] * tanhf((cv[i] - bcC[row][0]) * bcC[row][1] * ogv + obv);
        fout[(size_t)(bq*16 + row) * 1024 + (size_t)d*512 + scol] = h;
      }
    }
  }
}

extern "C" void kernel_launch(void* const* d_in, const int* in_sizes, int n_in,
                              void* d_out, int out_size, void* d_ws, size_t ws_size,
                              hipStream_t stream) {
  const float* x        = (const float*)d_in[0];
  const float* w_ih0    = (const float*)d_in[2];
  const float* w_hh0    = (const float*)d_in[3];
  const float* ln_ih0_g = (const float*)d_in[4];
  const float* ln_ih0_b = (const float*)d_in[5];
  const float* ln_hh0_g = (const float*)d_in[6];
  const float* ln_hh0_b = (const float*)d_in[7];
  const float* ln_ho0_g = (const float*)d_in[8];
  const float* ln_ho0_b = (const float*)d_in[9];
  const float* w_ih1    = (const float*)d_in[10];
  const float* w_hh1    = (const float*)d_in[11];
  const float* ln_ih1_g = (const float*)d_in[12];
  const float* ln_ih1_b = (const float*)d_in[13];
  const float* ln_hh1_g = (const float*)d_in[14];
  const float* ln_hh1_b = (const float*)d_in[15];
  const float* ln_ho1_g = (const float*)d_in[16];
  const float* ln_ho1_b = (const float*)d_in[17];
  float* out = (float*)d_out;

  // ws (floats): G0 12.58M | g1pre 262K | xcb 64K | Rpart 8K |
  //   [zero region: Cpart 8K | cbuf 64K | obuf 64K | cnt 1024 ints]  ~= 52.2 MB
  float* G0    = (float*)d_ws;
  float* g1pre = G0 + (size_t)2*BB*SS*G4;
  float* xcb   = g1pre + (size_t)2*BB*G4;
  float* Rpart = xcb + (size_t)BB*1024;
  float* Cpart = Rpart + (size_t)128*32*2;
  float* cbuf  = Cpart + (size_t)128*32*2;
  float* obuf  = cbuf + (size_t)128*512;
  int*   cnt   = (int*)(obuf + (size_t)128*512);
  // counters: L0 scan [0..256), L1 scan [256..512), preamble [512..544)

  // zero Cpart + cbuf + obuf + all counters
  hipMemsetAsync(Cpart, 0, ((size_t)128*32*2 + 2*(size_t)128*512)*sizeof(float)
                           + 1024*sizeof(int), stream);

  // phase A: G0 = LN(x @ w_ih0^T), time-reversal baked in for d=1
  hipLaunchKernelGGL(gemm_ih0, dim3(G4/64, (2*BB*SS)/64), dim3(256), 0, stream,
      x, w_ih0, G0);
  hipLaunchKernelGGL(ln_rows, dim3(2*BB*SS), dim3(256), 0, stream,
      G0, ln_ih0_g, ln_ih0_b, BB*SS);

  // layer 0 scan -> xcb
  hipLaunchKernelGGL(persist4, dim3(256), dim3(1024), 0, stream,
      w_hh0, G0, (long)SS*G4, (long)G4,
      ln_hh0_g, ln_hh0_b, ln_ho0_g, ln_ho0_b,
      cbuf, obuf, Rpart, Cpart, cnt, xcb, SS,
      0, (const float*)nullptr, (const float*)nullptr, (float*)nullptr,
      (const float*)nullptr, (const float*)nullptr, (int*)nullptr);

  // re-zero Cpart + cbuf + obuf for layer 1 (counters: L1 has its own region)
  hipMemsetAsync(Cpart, 0, ((size_t)128*32*2 + 2*(size_t)128*512)*sizeof(float), stream);

  // layer 1: projection + LN in preamble, then scan (t-stride 0) -> out
  hipLaunchKernelGGL(persist4, dim3(256), dim3(1024), 0, stream,
      w_hh1, g1pre, (long)G4, 0L,
      ln_hh1_g, ln_hh1_b, ln_ho1_g, ln_ho1_b,
      cbuf, obuf, Rpart, Cpart, cnt + 256, out, SS,
      1, w_ih1, xcb, g1pre, ln_ih1_g, ln_ih1_b, cnt + 512);
}